// Round 13
// baseline (370.898 us; speedup 1.0000x reference)
//
#include <hip/hip_runtime.h>
#include <math.h>

// ---------------------------------------------------------------------------
// Decoder block: x -> QKV proj -> causal MHA -> a + LN(a) -> FFN -> f + LN(f)
// B=2 T=2048 C=1024 NH=16 hd=64 DFF=4096, fp32 in/out.
// Round 13: push thin GEMMs to 8 blocks/CU (the lever that won rounds 5/7/8):
//   * FFN2 -> <32,64> tile: grid (16,128)=2048 blocks, LDS 12 KB -> occupancy
//     capped only by the 32-wave slots (was grid-capped at 38%).
//   * FFN1 -> <64,128>: grid (32,64)=2048 blocks, LDS 24 KB -> 6 blocks/CU.
//   * Staging generalized: TM/16 (TN/16) chunks assigned round-robin to waves
//     with a wave-uniform guard (needed for TM=32: 2 chunks, 4 waves). The
//     per-chunk wave-uniform global_load_lds pattern is unchanged.
// Evidence: occupancy tracked FFN2 dur 110->94->76->70 across 1->2->4 blk/CU;
// NP=4 (occupancy loss) and split-K (traffic) both regressed — don't revisit.
// ---------------------------------------------------------------------------

typedef __attribute__((ext_vector_type(8))) short short8;
typedef __attribute__((ext_vector_type(4))) float f32x4;

__device__ __forceinline__ unsigned short f2bf(float f) {
    unsigned u = __builtin_bit_cast(unsigned, f);
    unsigned r = u + 0x7fffu + ((u >> 16) & 1u);   // RNE
    return (unsigned short)(r >> 16);
}

// ---------------------------------------------------------------------------
// Merged preprocessing. Grid = 15368 blocks of 256:
//   [0,4096) x convert | [4096,7168) Wq/Wk/Wv transposes | [7168,15360) W1/W2
//   [15360,15368) bias concat
// ---------------------------------------------------------------------------
__global__ __launch_bounds__(256) void prep_kernel(
    const float* __restrict__ x,  const float* __restrict__ Wq,
    const float* __restrict__ Wk, const float* __restrict__ Wv,
    const float* __restrict__ W1, const float* __restrict__ W2,
    const float* __restrict__ bq, const float* __restrict__ bk,
    unsigned short* __restrict__ x_bf,  unsigned short* __restrict__ Wqk_t,
    unsigned short* __restrict__ Wvt,   unsigned short* __restrict__ W1t,
    unsigned short* __restrict__ W2t,   float* __restrict__ bqk)
{
    const int bid = blockIdx.x;
    const int tid = threadIdx.x;

    if (bid < 4096) {                       // x convert
        const int i = (bid * 256 + tid) * 4;
        float4 v = *(const float4*)(x + i);
        ushort4 o;
        o.x = f2bf(v.x); o.y = f2bf(v.y); o.z = f2bf(v.z); o.w = f2bf(v.w);
        *(ushort4*)(x_bf + i) = o;
        return;
    }
    if (bid >= 15360) {                     // bias concat
        const int i = (bid - 15360) * 256 + tid;
        bqk[i] = i < 1024 ? bq[i] : bk[i - 1024];
        return;
    }

    __shared__ float tile[32][33];
    const float* src; unsigned short* dst; int K, N, t;
    if (bid < 5120)       { t = bid - 4096;  src = Wq; dst = Wqk_t;            K = 1024; N = 1024; }
    else if (bid < 6144)  { t = bid - 5120;  src = Wk; dst = Wqk_t + 1048576;  K = 1024; N = 1024; }
    else if (bid < 7168)  { t = bid - 6144;  src = Wv; dst = Wvt;              K = 1024; N = 1024; }
    else if (bid < 11264) { t = bid - 7168;  src = W1; dst = W1t;              K = 1024; N = 4096; }
    else                  { t = bid - 11264; src = W2; dst = W2t;              K = 4096; N = 1024; }

    const int ncols = N >> 5;
    const int n0 = (t % ncols) * 32;
    const int k0 = (t / ncols) * 32;
    const int tx = tid & 31;
    const int ty = tid >> 5;                // 0..7
#pragma unroll
    for (int i = 0; i < 4; ++i)
        tile[ty + i * 8][tx] = src[(size_t)(k0 + ty + i * 8) * N + n0 + tx];
    __syncthreads();
#pragma unroll
    for (int i = 0; i < 4; ++i)
        dst[(size_t)(n0 + ty + i * 8) * K + k0 + tx] = f2bf(tile[tx][ty + i * 8]);
}

// ---------------------------------------------------------------------------
// GEMM body: C[M][N] = A[M][K] . Bt[N][K]^T + bias. TMxTN tile at (bx, by),
// K-loop unrolled NP x (NP 32-wide LDS planes per barrier pair).
// Staging: TM/16 A-chunks and TN/16 B-chunks of 16 rows assigned round-robin
// to the 4 waves (wave-uniform guard handles TM or TN = 32).
// mode: 0 = fp32 out, bias[col]; 1 = relu->bf16, bias[col];
//       2 = bf16, bias[col];     3 = bf16, bias[row].
// ---------------------------------------------------------------------------
template <int TM, int TN, int NP>
__device__ __forceinline__ void gemm_body(
    unsigned short* AsB, unsigned short* BsB,
    const unsigned short* __restrict__ A, const unsigned short* __restrict__ Bt,
    const float* __restrict__ bias, float* __restrict__ Cf,
    unsigned short* __restrict__ Cb, int M, int N, int K, int mode,
    int bx, int by)
{
    constexpr int NI   = TM / 32;                 // MFMA row-tiles per wave
    constexpr int NJ   = TN / 32;                 // MFMA col-tiles per wave
    constexpr int NCA  = TM / 16;                 // A staging chunks (total)
    constexpr int NCB  = TN / 16;                 // B staging chunks (total)
    constexpr int MAXA = (NCA + 3) / 4;           // chunks per wave (ceil)
    constexpr int MAXB = (NCB + 3) / 4;

    const int tid  = threadIdx.x;
    const int lane = tid & 63;
    const int w    = tid >> 6;
    const int wm   = (w & 1) * (TM / 2);
    const int wn   = (w >> 1) * (TN / 2);
    const int fm   = lane & 15;
    const int quad = lane >> 4;

    const int row0 = by * TM;
    const int col0 = bx * TN;

    const int srow = lane >> 2;          // lane -> row within 16-row chunk
    const int scol = (lane & 3) * 8;     // lane -> 8-short column group

    const unsigned short* aptr[MAXA];
    int aoff[MAXA];
#pragma unroll
    for (int i = 0; i < MAXA; ++i) {
        const int c = w + i * 4;
        if (c < NCA) {
            aptr[i] = A + (size_t)(row0 + c * 16 + srow) * K + scol;
            aoff[i] = c * 16 * 32;
        }
    }
    const unsigned short* bptr[MAXB];
    int boff[MAXB];
#pragma unroll
    for (int i = 0; i < MAXB; ++i) {
        const int c = w + i * 4;
        if (c < NCB) {
            bptr[i] = Bt + (size_t)(col0 + c * 16 + srow) * K + scol;
            boff[i] = c * 16 * 32;
        }
    }

    f32x4 acc[NI][NJ] = {};

    for (int k0 = 0; k0 < K; k0 += NP * 32) {
        __syncthreads();
#pragma unroll
        for (int p = 0; p < NP; ++p) {
#pragma unroll
            for (int i = 0; i < MAXA; ++i)
                if (w + i * 4 < NCA)          // wave-uniform
                    __builtin_amdgcn_global_load_lds(
                        (const __attribute__((address_space(1))) void*)(aptr[i] + k0 + p * 32),
                        (__attribute__((address_space(3))) void*)&AsB[p * TM * 32 + aoff[i]], 16, 0, 0);
#pragma unroll
            for (int i = 0; i < MAXB; ++i)
                if (w + i * 4 < NCB)          // wave-uniform
                    __builtin_amdgcn_global_load_lds(
                        (const __attribute__((address_space(1))) void*)(bptr[i] + k0 + p * 32),
                        (__attribute__((address_space(3))) void*)&BsB[p * TN * 32 + boff[i]], 16, 0, 0);
        }
        __syncthreads();

#pragma unroll
        for (int p = 0; p < NP; ++p) {
            short8 af[NI], bf[NJ];
#pragma unroll
            for (int i = 0; i < NI; ++i)
                af[i] = *(const short8*)&AsB[p * TM * 32 + (wm + i * 16 + fm) * 32 + quad * 8];
#pragma unroll
            for (int j = 0; j < NJ; ++j)
                bf[j] = *(const short8*)&BsB[p * TN * 32 + (wn + j * 16 + fm) * 32 + quad * 8];
#pragma unroll
            for (int i = 0; i < NI; ++i)
#pragma unroll
                for (int j = 0; j < NJ; ++j)
                    acc[i][j] = __builtin_amdgcn_mfma_f32_16x16x32_bf16(
                        af[i], bf[j], acc[i][j], 0, 0, 0);
        }
    }

    // Epilogue. C/D layout: col = lane&15, row = quad*4 + reg.
#pragma unroll
    for (int j = 0; j < NJ; ++j) {
        const int col = col0 + wn + j * 16 + fm;
        const float bcol = (mode == 3) ? 0.f : bias[col];
#pragma unroll
        for (int i = 0; i < NI; ++i) {
            const int rbase = row0 + wm + i * 16 + quad * 4;
#pragma unroll
            for (int r = 0; r < 4; ++r) {
                const int row = rbase + r;
                float val = acc[i][j][r] + ((mode == 3) ? bias[row] : bcol);
                if (mode == 1) val = fmaxf(val, 0.f);
                if (mode == 0) Cf[(size_t)row * N + col] = val;
                else           Cb[(size_t)row * N + col] = f2bf(val);
            }
        }
    }
}

template <int TM, int TN, int NP>
__global__ __launch_bounds__(256) void gemm_bf16_mfma(
    const unsigned short* __restrict__ A, const unsigned short* __restrict__ Bt,
    const float* __restrict__ bias, float* __restrict__ Cf,
    unsigned short* __restrict__ Cb, int M, int N, int K, int mode)
{
    __shared__ unsigned short As[NP * TM * 32];
    __shared__ unsigned short Bs[NP * TN * 32];
    gemm_body<TM, TN, NP>(As, Bs, A, Bt, bias, Cf, Cb, M, N, K, mode,
                          blockIdx.x, blockIdx.y);
}

// Two independent GEMMs (same tile config) in one flat-grid dispatch.
template <int TM, int TN, int NP>
__global__ __launch_bounds__(256) void gemm_dual(
    const unsigned short* __restrict__ A0, const unsigned short* __restrict__ B0,
    const float* __restrict__ bias0, unsigned short* __restrict__ C0,
    int M0, int N0, int K0, int mode0, int nb0, int nx0,
    const unsigned short* __restrict__ A1, const unsigned short* __restrict__ B1,
    const float* __restrict__ bias1, unsigned short* __restrict__ C1,
    int M1, int N1, int K1, int mode1, int nx1)
{
    __shared__ unsigned short As[NP * TM * 32];
    __shared__ unsigned short Bs[NP * TN * 32];
    const int bid = blockIdx.x;
    if (bid < nb0) {
        gemm_body<TM, TN, NP>(As, Bs, A0, B0, bias0, nullptr, C0,
                              M0, N0, K0, mode0, bid % nx0, bid / nx0);
    } else {
        const int t = bid - nb0;
        gemm_body<TM, TN, NP>(As, Bs, A1, B1, bias1, nullptr, C1,
                              M1, N1, K1, mode1, t % nx1, t / nx1);
    }
}

// ---------------------------------------------------------------------------
// MFMA flash attention v2. qk: [4096][2048] bf16 (q cols 0..1023, k 1024..),
// vt: [1024][4096] bf16 (row = h*64+d, col = b*2048+t), a: [4096][1024] fp32.
// No-max softmax (scores bounded); l via ones-B MFMA; S^T orientation so P
// stores are packed ds_write_b64.
// ---------------------------------------------------------------------------
__global__ __launch_bounds__(256) void fattn_mfma(
    const unsigned short* __restrict__ qk,
    const unsigned short* __restrict__ vt,
    float* __restrict__ a)
{
    const int T = 2048, LDQK = 2048, LDVT = 4096, OUTC = 1024;
    const float cs = 0.04508422f;       // (1/32) * log2(e)

    __shared__ unsigned short Qs[2][64][32];
    __shared__ unsigned short Ks[2][64][32];
    __shared__ unsigned short Vs[2][64][32];
    __shared__ unsigned short Ps[4][16][72];

    const int tid  = threadIdx.x;
    const int lane = tid & 63;
    const int w    = tid >> 6;
    const int fm   = lane & 15;
    const int quad = lane >> 4;
    const int srow = lane >> 2;
    const int scol = (lane & 3) * 8;

    const int n  = blockIdx.x;
    const int lo = n & 255, hi = n >> 8;
    const int h  = ((lo >> 5) & 7) | ((hi & 1) << 3);
    const int b  = hi >> 1;
    const int qv = lo & 31;
    const int u  = ((qv & 1) << 4) | ((qv & 2) << 2) | (qv & 4) |
                   ((qv & 8) >> 2) | ((qv & 16) >> 4);
    const int qb = (hi & 1) ? (31 - u) : u;
    const int q0 = qb * 64;

    const size_t rowbase = (size_t)b * T;

#pragma unroll
    for (int i = 0; i < 2; ++i) {
        const int c  = w * 2 + i;
        const int kh = c & 1, rg = c >> 1;
        const unsigned short* src = qk + (rowbase + q0 + rg * 16 + srow) * LDQK
                                       + h * 64 + kh * 32 + scol;
        __builtin_amdgcn_global_load_lds(
            (const __attribute__((address_space(1))) void*)src,
            (__attribute__((address_space(3))) void*)&Qs[kh][rg * 16][0], 16, 0, 0);
    }
    __syncthreads();
    short8 qf0 = *(const short8*)&Qs[0][w * 16 + fm][quad * 8];
    short8 qf1 = *(const short8*)&Qs[1][w * 16 + fm][quad * 8];

    short8 ones;
#pragma unroll
    for (int i = 0; i < 8; ++i) ones[i] = (short)0x3F80;   // bf16 1.0

    f32x4 o[4] = {};
    f32x4 lacc = {};

    const int qglob = q0 + w * 16 + fm;

    for (int jt = 0; jt <= qb; ++jt) {
        const int j0 = jt * 64;
        __syncthreads();
#pragma unroll
        for (int i = 0; i < 2; ++i) {
            const int c  = w * 2 + i;
            const int kh = c & 1, rg = c >> 1;
            const unsigned short* ksrc = qk + (rowbase + j0 + rg * 16 + srow) * LDQK
                                            + 1024 + h * 64 + kh * 32 + scol;
            __builtin_amdgcn_global_load_lds(
                (const __attribute__((address_space(1))) void*)ksrc,
                (__attribute__((address_space(3))) void*)&Ks[kh][rg * 16][0], 16, 0, 0);
            const unsigned short* vsrc = vt + (size_t)(h * 64 + rg * 16 + srow) * LDVT
                                            + rowbase + j0 + kh * 32 + scol;
            __builtin_amdgcn_global_load_lds(
                (const __attribute__((address_space(1))) void*)vsrc,
                (__attribute__((address_space(3))) void*)&Vs[kh][rg * 16][0], 16, 0, 0);
        }
        __syncthreads();

        // S^T = K . Q^T
        f32x4 s[4];
#pragma unroll
        for (int j = 0; j < 4; ++j) {
            short8 k0 = *(const short8*)&Ks[0][j * 16 + fm][quad * 8];
            short8 k1 = *(const short8*)&Ks[1][j * 16 + fm][quad * 8];
            f32x4 acc = {};
            acc = __builtin_amdgcn_mfma_f32_16x16x32_bf16(k0, qf0, acc, 0, 0, 0);
            acc = __builtin_amdgcn_mfma_f32_16x16x32_bf16(k1, qf1, acc, 0, 0, 0);
            s[j] = acc;
        }

        if (jt == qb) {
#pragma unroll
            for (int j = 0; j < 4; ++j) {
                const int kbase = j0 + j * 16 + quad * 4;
#pragma unroll
                for (int r = 0; r < 4; ++r) {
                    const float e = exp2f(s[j][r] * cs);
                    s[j][r] = (kbase + r > qglob) ? 0.f : e;
                }
            }
        } else {
#pragma unroll
            for (int j = 0; j < 4; ++j)
#pragma unroll
                for (int r = 0; r < 4; ++r)
                    s[j][r] = exp2f(s[j][r] * cs);
        }

#pragma unroll
        for (int j = 0; j < 4; ++j) {
            const unsigned d0 = (unsigned)f2bf(s[j][0]) | ((unsigned)f2bf(s[j][1]) << 16);
            const unsigned d1 = (unsigned)f2bf(s[j][2]) | ((unsigned)f2bf(s[j][3]) << 16);
            *(uint2*)&Ps[w][fm][j * 16 + quad * 4] = make_uint2(d0, d1);
        }
        short8 pf0 = *(const short8*)&Ps[w][fm][quad * 8];
        short8 pf1 = *(const short8*)&Ps[w][fm][32 + quad * 8];

#pragma unroll
        for (int jd = 0; jd < 4; ++jd) {
            short8 v0 = *(const short8*)&Vs[0][jd * 16 + fm][quad * 8];
            short8 v1 = *(const short8*)&Vs[1][jd * 16 + fm][quad * 8];
            o[jd] = __builtin_amdgcn_mfma_f32_16x16x32_bf16(pf0, v0, o[jd], 0, 0, 0);
            o[jd] = __builtin_amdgcn_mfma_f32_16x16x32_bf16(pf1, v1, o[jd], 0, 0, 0);
        }
        lacc = __builtin_amdgcn_mfma_f32_16x16x32_bf16(pf0, ones, lacc, 0, 0, 0);
        lacc = __builtin_amdgcn_mfma_f32_16x16x32_bf16(pf1, ones, lacc, 0, 0, 0);
    }

    const size_t orow = rowbase + q0 + w * 16 + quad * 4;
#pragma unroll
    for (int r = 0; r < 4; ++r) {
        const float inv = 1.0f / lacc[r];
#pragma unroll
        for (int jd = 0; jd < 4; ++jd)
            a[(orow + r) * OUTC + h * 64 + jd * 16 + fm] = o[jd][r] * inv;
    }
}

// out = in + LayerNorm(in)*w. bf16_out=1 -> write bf16 to outb, else fp32 outf.
__global__ __launch_bounds__(256) void add_ln_kernel(
    const float* __restrict__ in, const float* __restrict__ w,
    float* __restrict__ outf, unsigned short* __restrict__ outb, int bf16_out)
{
    const int C = 1024;
    const int row = blockIdx.x;
    const int tid = threadIdx.x;

    __shared__ float red[256];

    const float* x = in + (size_t)row * C;
    float4 xv = *(const float4*)(x + tid * 4);

    red[tid] = xv.x + xv.y + xv.z + xv.w;
    __syncthreads();
    for (int off = 128; off > 0; off >>= 1) {
        if (tid < off) red[tid] += red[tid + off];
        __syncthreads();
    }
    const float mu = red[0] * (1.0f / 1024.0f);
    __syncthreads();

    float dx = xv.x - mu, dy = xv.y - mu, dz = xv.z - mu, dw = xv.w - mu;
    red[tid] = dx * dx + dy * dy + dz * dz + dw * dw;
    __syncthreads();
    for (int off = 128; off > 0; off >>= 1) {
        if (tid < off) red[tid] += red[tid + off];
        __syncthreads();
    }
    const float rstd = rsqrtf(red[0] * (1.0f / 1024.0f) + 1e-5f);

    float4 wv = *(const float4*)(w + tid * 4);
    float ox = xv.x + dx * rstd * wv.x;
    float oy = xv.y + dy * rstd * wv.y;
    float oz = xv.z + dz * rstd * wv.z;
    float ow = xv.w + dw * rstd * wv.w;
    if (bf16_out) {
        ushort4 o4;
        o4.x = f2bf(ox); o4.y = f2bf(oy); o4.z = f2bf(oz); o4.w = f2bf(ow);
        *(ushort4*)(outb + (size_t)row * C + tid * 4) = o4;
    } else {
        *(float4*)(outf + (size_t)row * C + tid * 4) = make_float4(ox, oy, oz, ow);
    }
}

extern "C" void kernel_launch(void* const* d_in, const int* in_sizes, int n_in,
                              void* d_out, int out_size, void* d_ws, size_t ws_size,
                              hipStream_t stream)
{
    const float* x    = (const float*)d_in[0];
    const float* Wq   = (const float*)d_in[1];
    const float* bq   = (const float*)d_in[2];
    const float* Wk   = (const float*)d_in[3];
    const float* bk   = (const float*)d_in[4];
    const float* Wv   = (const float*)d_in[5];
    const float* bv   = (const float*)d_in[6];
    const float* W1   = (const float*)d_in[7];
    const float* b1   = (const float*)d_in[8];
    const float* W2   = (const float*)d_in[9];
    const float* b2   = (const float*)d_in[10];
    const float* ln_w = (const float*)d_in[11];
    float* out = (float*)d_out;
    char* ws = (char*)d_ws;

    const int B = 2, T = 2048, C = 1024, DFF = 4096;
    const int M = B * T;                 // 4096
    const size_t MB = 1048576;

    unsigned short* qk_bf = (unsigned short*)(ws);             // 16 MB [4096][2048]
    unsigned short* vt_bf = (unsigned short*)(ws + 16 * MB);   //  8 MB [1024][4096]
    float*          a     = (float*)(ws + 24 * MB);            // 16 MB [4096][1024]
    unsigned short* x_bf  = (unsigned short*)(ws + 40 * MB);   //  8 MB [4096][1024]
    unsigned short* Wqk_t = (unsigned short*)(ws + 48 * MB);   //  4 MB [2048][1024]
    unsigned short* Wvt   = (unsigned short*)(ws + 52 * MB);   //  2 MB [1024][1024]
    unsigned short* W1t   = (unsigned short*)(ws + 54 * MB);   //  8 MB [4096][1024]
    unsigned short* W2t   = (unsigned short*)(ws + 62 * MB);   //  8 MB [1024][4096]
    float*          bqk   = (float*)(ws + 70 * MB);            //  8 KB [2048]
    unsigned short* u_bf  = (unsigned short*)(ws + 71 * MB);   // 32 MB [4096][4096]
    unsigned short* h_bf  = x_bf;                              // reuse (x dead)
    float*          f     = (float*)(ws);                      // 16 MB, reuse qk

    dim3 blk(256);

    // One merged preprocessing dispatch.
    prep_kernel<<<dim3(15368), blk, 0, stream>>>(
        x, Wq, Wk, Wv, W1, W2, bq, bk,
        x_bf, Wqk_t, Wvt, W1t, W2t, bqk);

    // QK projection + V^T in one dual dispatch, both <64,64,2>:
    //   QK:  [4096,1024]x[1024,2048] -> bf16, mode 2. grid 32x64 = 2048 blocks.
    //   V^T: vt[d][t] = Wv^T . x^T,  bias-by-row, mode 3. grid 64x16 = 1024.
    gemm_dual<64, 64, 2><<<dim3(3072), blk, 0, stream>>>(
        x_bf, Wqk_t, bqk, qk_bf, M, 2 * C, C, 2, 2048, 32,
        Wvt, x_bf, bv, vt_bf, C, M, C, 3, 64);

    fattn_mfma<<<dim3(1024), blk, 0, stream>>>(qk_bf, vt_bf, a);

    add_ln_kernel<<<dim3(M), blk, 0, stream>>>(a, ln_w, nullptr, h_bf, 1);

    // FFN1: [4096,1024] x [1024,4096] -> relu -> bf16. <64,128> -> (32,64)=2048.
    gemm_bf16_mfma<64, 128, 2><<<dim3(DFF / 128, M / 64), blk, 0, stream>>>(
        h_bf, W1t, b1, nullptr, u_bf, M, DFF, C, 1);

    // FFN2: [4096,4096] x [4096,1024] -> fp32. <32,64> -> (16,128)=2048 (8/CU).
    gemm_bf16_mfma<32, 64, 2><<<dim3(C / 64, M / 32), blk, 0, stream>>>(
        u_bf, W2t, b2, f, nullptr, M, C, DFF, 0);

    add_ln_kernel<<<dim3(M), blk, 0, stream>>>(f, ln_w, out, nullptr, 0);
}

// Round 14
// 332.386 us; speedup vs baseline: 1.1159x; 1.1159x over previous
//
#include <hip/hip_runtime.h>
#include <math.h>

// ---------------------------------------------------------------------------
// Decoder block: x -> QKV proj -> causal MHA -> a + LN(a) -> FFN -> f + LN(f)
// B=2 T=2048 C=1024 NH=16 hd=64 DFF=4096, fp32 in/out.
// Round 14:
//   * REVERT FFN2 <32,64> -> <64,64,2> (A/B: 94 vs 69.5 us; at <32,64> the
//     per-barrier MFMA density halves — occupancy lever is exhausted).
//   * FFN2 launched flat with an XCD-aware swizzle: bid&7 selects the XCD
//     (HW round-robin, m09); each XCD gets a compact 16col x 8row region so
//     its 4 MB L2 holds the A/B working set. Round-13 counters showed 137 MB
//     FETCH vs 40 MB ideal (3.4x overfetch) on FFN2.
//   * FFN1 stays <64,128,2> (round-13 residual says ~3 us gain).
// ---------------------------------------------------------------------------

typedef __attribute__((ext_vector_type(8))) short short8;
typedef __attribute__((ext_vector_type(4))) float f32x4;

__device__ __forceinline__ unsigned short f2bf(float f) {
    unsigned u = __builtin_bit_cast(unsigned, f);
    unsigned r = u + 0x7fffu + ((u >> 16) & 1u);   // RNE
    return (unsigned short)(r >> 16);
}

// ---------------------------------------------------------------------------
// Merged preprocessing. Grid = 15368 blocks of 256.
// ---------------------------------------------------------------------------
__global__ __launch_bounds__(256) void prep_kernel(
    const float* __restrict__ x,  const float* __restrict__ Wq,
    const float* __restrict__ Wk, const float* __restrict__ Wv,
    const float* __restrict__ W1, const float* __restrict__ W2,
    const float* __restrict__ bq, const float* __restrict__ bk,
    unsigned short* __restrict__ x_bf,  unsigned short* __restrict__ Wqk_t,
    unsigned short* __restrict__ Wvt,   unsigned short* __restrict__ W1t,
    unsigned short* __restrict__ W2t,   float* __restrict__ bqk)
{
    const int bid = blockIdx.x;
    const int tid = threadIdx.x;

    if (bid < 4096) {                       // x convert
        const int i = (bid * 256 + tid) * 4;
        float4 v = *(const float4*)(x + i);
        ushort4 o;
        o.x = f2bf(v.x); o.y = f2bf(v.y); o.z = f2bf(v.z); o.w = f2bf(v.w);
        *(ushort4*)(x_bf + i) = o;
        return;
    }
    if (bid >= 15360) {                     // bias concat
        const int i = (bid - 15360) * 256 + tid;
        bqk[i] = i < 1024 ? bq[i] : bk[i - 1024];
        return;
    }

    __shared__ float tile[32][33];
    const float* src; unsigned short* dst; int K, N, t;
    if (bid < 5120)       { t = bid - 4096;  src = Wq; dst = Wqk_t;            K = 1024; N = 1024; }
    else if (bid < 6144)  { t = bid - 5120;  src = Wk; dst = Wqk_t + 1048576;  K = 1024; N = 1024; }
    else if (bid < 7168)  { t = bid - 6144;  src = Wv; dst = Wvt;              K = 1024; N = 1024; }
    else if (bid < 11264) { t = bid - 7168;  src = W1; dst = W1t;              K = 1024; N = 4096; }
    else                  { t = bid - 11264; src = W2; dst = W2t;              K = 4096; N = 1024; }

    const int ncols = N >> 5;
    const int n0 = (t % ncols) * 32;
    const int k0 = (t / ncols) * 32;
    const int tx = tid & 31;
    const int ty = tid >> 5;                // 0..7
#pragma unroll
    for (int i = 0; i < 4; ++i)
        tile[ty + i * 8][tx] = src[(size_t)(k0 + ty + i * 8) * N + n0 + tx];
    __syncthreads();
#pragma unroll
    for (int i = 0; i < 4; ++i)
        dst[(size_t)(n0 + ty + i * 8) * K + k0 + tx] = f2bf(tile[tx][ty + i * 8]);
}

// ---------------------------------------------------------------------------
// GEMM body: C[M][N] = A[M][K] . Bt[N][K]^T + bias. TMxTN tile at (bx, by),
// K-loop unrolled NP x (NP 32-wide LDS planes per barrier pair).
// mode: 0 = fp32 out, bias[col]; 1 = relu->bf16, bias[col];
//       2 = bf16, bias[col];     3 = bf16, bias[row].
// ---------------------------------------------------------------------------
template <int TM, int TN, int NP>
__device__ __forceinline__ void gemm_body(
    unsigned short* AsB, unsigned short* BsB,
    const unsigned short* __restrict__ A, const unsigned short* __restrict__ Bt,
    const float* __restrict__ bias, float* __restrict__ Cf,
    unsigned short* __restrict__ Cb, int M, int N, int K, int mode,
    int bx, int by)
{
    constexpr int NI   = TM / 32;
    constexpr int NJ   = TN / 32;
    constexpr int NCA  = TM / 16;
    constexpr int NCB  = TN / 16;
    constexpr int MAXA = (NCA + 3) / 4;
    constexpr int MAXB = (NCB + 3) / 4;

    const int tid  = threadIdx.x;
    const int lane = tid & 63;
    const int w    = tid >> 6;
    const int wm   = (w & 1) * (TM / 2);
    const int wn   = (w >> 1) * (TN / 2);
    const int fm   = lane & 15;
    const int quad = lane >> 4;

    const int row0 = by * TM;
    const int col0 = bx * TN;

    const int srow = lane >> 2;
    const int scol = (lane & 3) * 8;

    const unsigned short* aptr[MAXA];
    int aoff[MAXA];
#pragma unroll
    for (int i = 0; i < MAXA; ++i) {
        const int c = w + i * 4;
        if (c < NCA) {
            aptr[i] = A + (size_t)(row0 + c * 16 + srow) * K + scol;
            aoff[i] = c * 16 * 32;
        }
    }
    const unsigned short* bptr[MAXB];
    int boff[MAXB];
#pragma unroll
    for (int i = 0; i < MAXB; ++i) {
        const int c = w + i * 4;
        if (c < NCB) {
            bptr[i] = Bt + (size_t)(col0 + c * 16 + srow) * K + scol;
            boff[i] = c * 16 * 32;
        }
    }

    f32x4 acc[NI][NJ] = {};

    for (int k0 = 0; k0 < K; k0 += NP * 32) {
        __syncthreads();
#pragma unroll
        for (int p = 0; p < NP; ++p) {
#pragma unroll
            for (int i = 0; i < MAXA; ++i)
                if (w + i * 4 < NCA)          // wave-uniform
                    __builtin_amdgcn_global_load_lds(
                        (const __attribute__((address_space(1))) void*)(aptr[i] + k0 + p * 32),
                        (__attribute__((address_space(3))) void*)&AsB[p * TM * 32 + aoff[i]], 16, 0, 0);
#pragma unroll
            for (int i = 0; i < MAXB; ++i)
                if (w + i * 4 < NCB)          // wave-uniform
                    __builtin_amdgcn_global_load_lds(
                        (const __attribute__((address_space(1))) void*)(bptr[i] + k0 + p * 32),
                        (__attribute__((address_space(3))) void*)&BsB[p * TN * 32 + boff[i]], 16, 0, 0);
        }
        __syncthreads();

#pragma unroll
        for (int p = 0; p < NP; ++p) {
            short8 af[NI], bf[NJ];
#pragma unroll
            for (int i = 0; i < NI; ++i)
                af[i] = *(const short8*)&AsB[p * TM * 32 + (wm + i * 16 + fm) * 32 + quad * 8];
#pragma unroll
            for (int j = 0; j < NJ; ++j)
                bf[j] = *(const short8*)&BsB[p * TN * 32 + (wn + j * 16 + fm) * 32 + quad * 8];
#pragma unroll
            for (int i = 0; i < NI; ++i)
#pragma unroll
                for (int j = 0; j < NJ; ++j)
                    acc[i][j] = __builtin_amdgcn_mfma_f32_16x16x32_bf16(
                        af[i], bf[j], acc[i][j], 0, 0, 0);
        }
    }

    // Epilogue. C/D layout: col = lane&15, row = quad*4 + reg.
#pragma unroll
    for (int j = 0; j < NJ; ++j) {
        const int col = col0 + wn + j * 16 + fm;
        const float bcol = (mode == 3) ? 0.f : bias[col];
#pragma unroll
        for (int i = 0; i < NI; ++i) {
            const int rbase = row0 + wm + i * 16 + quad * 4;
#pragma unroll
            for (int r = 0; r < 4; ++r) {
                const int row = rbase + r;
                float val = acc[i][j][r] + ((mode == 3) ? bias[row] : bcol);
                if (mode == 1) val = fmaxf(val, 0.f);
                if (mode == 0) Cf[(size_t)row * N + col] = val;
                else           Cb[(size_t)row * N + col] = f2bf(val);
            }
        }
    }
}

template <int TM, int TN, int NP>
__global__ __launch_bounds__(256) void gemm_bf16_mfma(
    const unsigned short* __restrict__ A, const unsigned short* __restrict__ Bt,
    const float* __restrict__ bias, float* __restrict__ Cf,
    unsigned short* __restrict__ Cb, int M, int N, int K, int mode)
{
    __shared__ unsigned short As[NP * TM * 32];
    __shared__ unsigned short Bs[NP * TN * 32];
    gemm_body<TM, TN, NP>(As, Bs, A, Bt, bias, Cf, Cb, M, N, K, mode,
                          blockIdx.x, blockIdx.y);
}

// Flat-grid GEMM with XCD-aware block swizzle: bid&7 = XCD (HW round-robin);
// each XCD covers a compact nx-col x (ny/8)-row region of the tile grid so
// its private L2 holds the A/B working set.
template <int TM, int TN, int NP>
__global__ __launch_bounds__(256) void gemm_xcd(
    const unsigned short* __restrict__ A, const unsigned short* __restrict__ Bt,
    const float* __restrict__ bias, float* __restrict__ Cf,
    unsigned short* __restrict__ Cb, int M, int N, int K, int mode,
    int nx, int rows_per_xcd)
{
    __shared__ unsigned short As[NP * TM * 32];
    __shared__ unsigned short Bs[NP * TN * 32];
    const int xcd = blockIdx.x & 7;
    const int idx = blockIdx.x >> 3;
    const int bx  = idx % nx;
    const int by  = xcd * rows_per_xcd + idx / nx;
    gemm_body<TM, TN, NP>(As, Bs, A, Bt, bias, Cf, Cb, M, N, K, mode, bx, by);
}

// Two independent GEMMs (same tile config) in one flat-grid dispatch.
template <int TM, int TN, int NP>
__global__ __launch_bounds__(256) void gemm_dual(
    const unsigned short* __restrict__ A0, const unsigned short* __restrict__ B0,
    const float* __restrict__ bias0, unsigned short* __restrict__ C0,
    int M0, int N0, int K0, int mode0, int nb0, int nx0,
    const unsigned short* __restrict__ A1, const unsigned short* __restrict__ B1,
    const float* __restrict__ bias1, unsigned short* __restrict__ C1,
    int M1, int N1, int K1, int mode1, int nx1)
{
    __shared__ unsigned short As[NP * TM * 32];
    __shared__ unsigned short Bs[NP * TN * 32];
    const int bid = blockIdx.x;
    if (bid < nb0) {
        gemm_body<TM, TN, NP>(As, Bs, A0, B0, bias0, nullptr, C0,
                              M0, N0, K0, mode0, bid % nx0, bid / nx0);
    } else {
        const int t = bid - nb0;
        gemm_body<TM, TN, NP>(As, Bs, A1, B1, bias1, nullptr, C1,
                              M1, N1, K1, mode1, t % nx1, t / nx1);
    }
}

// ---------------------------------------------------------------------------
// MFMA flash attention v2. qk: [4096][2048] bf16 (q cols 0..1023, k 1024..),
// vt: [1024][4096] bf16 (row = h*64+d, col = b*2048+t), a: [4096][1024] fp32.
// ---------------------------------------------------------------------------
__global__ __launch_bounds__(256) void fattn_mfma(
    const unsigned short* __restrict__ qk,
    const unsigned short* __restrict__ vt,
    float* __restrict__ a)
{
    const int T = 2048, LDQK = 2048, LDVT = 4096, OUTC = 1024;
    const float cs = 0.04508422f;       // (1/32) * log2(e)

    __shared__ unsigned short Qs[2][64][32];
    __shared__ unsigned short Ks[2][64][32];
    __shared__ unsigned short Vs[2][64][32];
    __shared__ unsigned short Ps[4][16][72];

    const int tid  = threadIdx.x;
    const int lane = tid & 63;
    const int w    = tid >> 6;
    const int fm   = lane & 15;
    const int quad = lane >> 4;
    const int srow = lane >> 2;
    const int scol = (lane & 3) * 8;

    const int n  = blockIdx.x;
    const int lo = n & 255, hi = n >> 8;
    const int h  = ((lo >> 5) & 7) | ((hi & 1) << 3);
    const int b  = hi >> 1;
    const int qv = lo & 31;
    const int u  = ((qv & 1) << 4) | ((qv & 2) << 2) | (qv & 4) |
                   ((qv & 8) >> 2) | ((qv & 16) >> 4);
    const int qb = (hi & 1) ? (31 - u) : u;
    const int q0 = qb * 64;

    const size_t rowbase = (size_t)b * T;

#pragma unroll
    for (int i = 0; i < 2; ++i) {
        const int c  = w * 2 + i;
        const int kh = c & 1, rg = c >> 1;
        const unsigned short* src = qk + (rowbase + q0 + rg * 16 + srow) * LDQK
                                       + h * 64 + kh * 32 + scol;
        __builtin_amdgcn_global_load_lds(
            (const __attribute__((address_space(1))) void*)src,
            (__attribute__((address_space(3))) void*)&Qs[kh][rg * 16][0], 16, 0, 0);
    }
    __syncthreads();
    short8 qf0 = *(const short8*)&Qs[0][w * 16 + fm][quad * 8];
    short8 qf1 = *(const short8*)&Qs[1][w * 16 + fm][quad * 8];

    short8 ones;
#pragma unroll
    for (int i = 0; i < 8; ++i) ones[i] = (short)0x3F80;   // bf16 1.0

    f32x4 o[4] = {};
    f32x4 lacc = {};

    const int qglob = q0 + w * 16 + fm;

    for (int jt = 0; jt <= qb; ++jt) {
        const int j0 = jt * 64;
        __syncthreads();
#pragma unroll
        for (int i = 0; i < 2; ++i) {
            const int c  = w * 2 + i;
            const int kh = c & 1, rg = c >> 1;
            const unsigned short* ksrc = qk + (rowbase + j0 + rg * 16 + srow) * LDQK
                                            + 1024 + h * 64 + kh * 32 + scol;
            __builtin_amdgcn_global_load_lds(
                (const __attribute__((address_space(1))) void*)ksrc,
                (__attribute__((address_space(3))) void*)&Ks[kh][rg * 16][0], 16, 0, 0);
            const unsigned short* vsrc = vt + (size_t)(h * 64 + rg * 16 + srow) * LDVT
                                            + rowbase + j0 + kh * 32 + scol;
            __builtin_amdgcn_global_load_lds(
                (const __attribute__((address_space(1))) void*)vsrc,
                (__attribute__((address_space(3))) void*)&Vs[kh][rg * 16][0], 16, 0, 0);
        }
        __syncthreads();

        // S^T = K . Q^T
        f32x4 s[4];
#pragma unroll
        for (int j = 0; j < 4; ++j) {
            short8 k0 = *(const short8*)&Ks[0][j * 16 + fm][quad * 8];
            short8 k1 = *(const short8*)&Ks[1][j * 16 + fm][quad * 8];
            f32x4 acc = {};
            acc = __builtin_amdgcn_mfma_f32_16x16x32_bf16(k0, qf0, acc, 0, 0, 0);
            acc = __builtin_amdgcn_mfma_f32_16x16x32_bf16(k1, qf1, acc, 0, 0, 0);
            s[j] = acc;
        }

        if (jt == qb) {
#pragma unroll
            for (int j = 0; j < 4; ++j) {
                const int kbase = j0 + j * 16 + quad * 4;
#pragma unroll
                for (int r = 0; r < 4; ++r) {
                    const float e = exp2f(s[j][r] * cs);
                    s[j][r] = (kbase + r > qglob) ? 0.f : e;
                }
            }
        } else {
#pragma unroll
            for (int j = 0; j < 4; ++j)
#pragma unroll
                for (int r = 0; r < 4; ++r)
                    s[j][r] = exp2f(s[j][r] * cs);
        }

#pragma unroll
        for (int j = 0; j < 4; ++j) {
            const unsigned d0 = (unsigned)f2bf(s[j][0]) | ((unsigned)f2bf(s[j][1]) << 16);
            const unsigned d1 = (unsigned)f2bf(s[j][2]) | ((unsigned)f2bf(s[j][3]) << 16);
            *(uint2*)&Ps[w][fm][j * 16 + quad * 4] = make_uint2(d0, d1);
        }
        short8 pf0 = *(const short8*)&Ps[w][fm][quad * 8];
        short8 pf1 = *(const short8*)&Ps[w][fm][32 + quad * 8];

#pragma unroll
        for (int jd = 0; jd < 4; ++jd) {
            short8 v0 = *(const short8*)&Vs[0][jd * 16 + fm][quad * 8];
            short8 v1 = *(const short8*)&Vs[1][jd * 16 + fm][quad * 8];
            o[jd] = __builtin_amdgcn_mfma_f32_16x16x32_bf16(pf0, v0, o[jd], 0, 0, 0);
            o[jd] = __builtin_amdgcn_mfma_f32_16x16x32_bf16(pf1, v1, o[jd], 0, 0, 0);
        }
        lacc = __builtin_amdgcn_mfma_f32_16x16x32_bf16(pf0, ones, lacc, 0, 0, 0);
        lacc = __builtin_amdgcn_mfma_f32_16x16x32_bf16(pf1, ones, lacc, 0, 0, 0);
    }

    const size_t orow = rowbase + q0 + w * 16 + quad * 4;
#pragma unroll
    for (int r = 0; r < 4; ++r) {
        const float inv = 1.0f / lacc[r];
#pragma unroll
        for (int jd = 0; jd < 4; ++jd)
            a[(orow + r) * OUTC + h * 64 + jd * 16 + fm] = o[jd][r] * inv;
    }
}

// out = in + LayerNorm(in)*w. bf16_out=1 -> write bf16 to outb, else fp32 outf.
__global__ __launch_bounds__(256) void add_ln_kernel(
    const float* __restrict__ in, const float* __restrict__ w,
    float* __restrict__ outf, unsigned short* __restrict__ outb, int bf16_out)
{
    const int C = 1024;
    const int row = blockIdx.x;
    const int tid = threadIdx.x;

    __shared__ float red[256];

    const float* x = in + (size_t)row * C;
    float4 xv = *(const float4*)(x + tid * 4);

    red[tid] = xv.x + xv.y + xv.z + xv.w;
    __syncthreads();
    for (int off = 128; off > 0; off >>= 1) {
        if (tid < off) red[tid] += red[tid + off];
        __syncthreads();
    }
    const float mu = red[0] * (1.0f / 1024.0f);
    __syncthreads();

    float dx = xv.x - mu, dy = xv.y - mu, dz = xv.z - mu, dw = xv.w - mu;
    red[tid] = dx * dx + dy * dy + dz * dz + dw * dw;
    __syncthreads();
    for (int off = 128; off > 0; off >>= 1) {
        if (tid < off) red[tid] += red[tid + off];
        __syncthreads();
    }
    const float rstd = rsqrtf(red[0] * (1.0f / 1024.0f) + 1e-5f);

    float4 wv = *(const float4*)(w + tid * 4);
    float ox = xv.x + dx * rstd * wv.x;
    float oy = xv.y + dy * rstd * wv.y;
    float oz = xv.z + dz * rstd * wv.z;
    float ow = xv.w + dw * rstd * wv.w;
    if (bf16_out) {
        ushort4 o4;
        o4.x = f2bf(ox); o4.y = f2bf(oy); o4.z = f2bf(oz); o4.w = f2bf(ow);
        *(ushort4*)(outb + (size_t)row * C + tid * 4) = o4;
    } else {
        *(float4*)(outf + (size_t)row * C + tid * 4) = make_float4(ox, oy, oz, ow);
    }
}

extern "C" void kernel_launch(void* const* d_in, const int* in_sizes, int n_in,
                              void* d_out, int out_size, void* d_ws, size_t ws_size,
                              hipStream_t stream)
{
    const float* x    = (const float*)d_in[0];
    const float* Wq   = (const float*)d_in[1];
    const float* bq   = (const float*)d_in[2];
    const float* Wk   = (const float*)d_in[3];
    const float* bk   = (const float*)d_in[4];
    const float* Wv   = (const float*)d_in[5];
    const float* bv   = (const float*)d_in[6];
    const float* W1   = (const float*)d_in[7];
    const float* b1   = (const float*)d_in[8];
    const float* W2   = (const float*)d_in[9];
    const float* b2   = (const float*)d_in[10];
    const float* ln_w = (const float*)d_in[11];
    float* out = (float*)d_out;
    char* ws = (char*)d_ws;

    const int B = 2, T = 2048, C = 1024, DFF = 4096;
    const int M = B * T;                 // 4096
    const size_t MB = 1048576;

    unsigned short* qk_bf = (unsigned short*)(ws);             // 16 MB [4096][2048]
    unsigned short* vt_bf = (unsigned short*)(ws + 16 * MB);   //  8 MB [1024][4096]
    float*          a     = (float*)(ws + 24 * MB);            // 16 MB [4096][1024]
    unsigned short* x_bf  = (unsigned short*)(ws + 40 * MB);   //  8 MB [4096][1024]
    unsigned short* Wqk_t = (unsigned short*)(ws + 48 * MB);   //  4 MB [2048][1024]
    unsigned short* Wvt   = (unsigned short*)(ws + 52 * MB);   //  2 MB [1024][1024]
    unsigned short* W1t   = (unsigned short*)(ws + 54 * MB);   //  8 MB [4096][1024]
    unsigned short* W2t   = (unsigned short*)(ws + 62 * MB);   //  8 MB [1024][4096]
    float*          bqk   = (float*)(ws + 70 * MB);            //  8 KB [2048]
    unsigned short* u_bf  = (unsigned short*)(ws + 71 * MB);   // 32 MB [4096][4096]
    unsigned short* h_bf  = x_bf;                              // reuse (x dead)
    float*          f     = (float*)(ws);                      // 16 MB, reuse qk

    dim3 blk(256);

    // One merged preprocessing dispatch.
    prep_kernel<<<dim3(15368), blk, 0, stream>>>(
        x, Wq, Wk, Wv, W1, W2, bq, bk,
        x_bf, Wqk_t, Wvt, W1t, W2t, bqk);

    // QK projection + V^T in one dual dispatch, both <64,64,2>.
    gemm_dual<64, 64, 2><<<dim3(3072), blk, 0, stream>>>(
        x_bf, Wqk_t, bqk, qk_bf, M, 2 * C, C, 2, 2048, 32,
        Wvt, x_bf, bv, vt_bf, C, M, C, 3, 64);

    fattn_mfma<<<dim3(1024), blk, 0, stream>>>(qk_bf, vt_bf, a);

    add_ln_kernel<<<dim3(M), blk, 0, stream>>>(a, ln_w, nullptr, h_bf, 1);

    // FFN1: [4096,1024] x [1024,4096] -> relu -> bf16. <64,128> (32,64)=2048.
    gemm_bf16_mfma<64, 128, 2><<<dim3(DFF / 128, M / 64), blk, 0, stream>>>(
        h_bf, W1t, b1, nullptr, u_bf, M, DFF, C, 1);

    // FFN2: [4096,4096] x [4096,1024] -> fp32. <64,64,2>, flat 1024 blocks
    // with XCD-aware swizzle (grid 16 cols x 64 rows; 8 rows per XCD).
    gemm_xcd<64, 64, 2><<<dim3(1024), blk, 0, stream>>>(
        u_bf, W2t, b2, f, nullptr, M, C, DFF, 0, 16, 8);

    add_ln_kernel<<<dim3(M), blk, 0, stream>>>(f, ln_w, out, nullptr, 0);
}